// Round 1
// baseline (1536.811 us; speedup 1.0000x reference)
//
#include <hip/hip_runtime.h>
#include <hip/hip_bf16.h>

#define T_DIM 512
#define H_DIM 4096
#define F_DIM 14336

typedef __attribute__((ext_vector_type(8))) short bf16x8;
typedef __attribute__((ext_vector_type(4))) float f32x4;

__device__ __forceinline__ unsigned short f2bf(float f) {
    union { float f; unsigned u; } v; v.f = f;
    unsigned r = v.u + 0x7fffu + ((v.u >> 16) & 1u);  // RNE
    return (unsigned short)(r >> 16);
}

// ---------------------------------------------------------------------------
// Kernel A: G = silu(X @ W1^T) * (X @ W3^T)   -> bf16 [T, F] in workspace
// Tile: BM=128 (T), BN=64 (F), BK=64 (=GROUP). 256 threads = 4 waves.
// Each wave owns a 32x64 quadrant: 2 (m) x 4 (n) MFMA tiles, for BOTH W1/W3.
// ---------------------------------------------------------------------------
__global__ __launch_bounds__(256, 2)
void gate_up_kernel(const float* __restrict__ X,
                    const int* __restrict__ W1q, const float* __restrict__ sc1,
                    const float* __restrict__ zp1,
                    const int* __restrict__ W3q, const float* __restrict__ sc3,
                    const float* __restrict__ zp3,
                    unsigned short* __restrict__ G)
{
    constexpr int LK = 72;                    // 64 + 8 pad (144 B stride, 16B aligned)
    __shared__ unsigned short sX[128 * LK];
    __shared__ unsigned short sW1[64 * LK];
    __shared__ unsigned short sW3[64 * LK];

    const int t    = threadIdx.x;
    const int wave = t >> 6;
    const int lane = t & 63;
    const int r    = lane & 15;               // fragment row/col index
    const int q    = lane >> 4;               // quad
    const int m0   = blockIdx.y * 128;
    const int n0   = blockIdx.x * 64;
    const int SG   = H_DIM / 64;              // scale groups per output row

    f32x4 acc1[2][4], acc3[2][4];
    #pragma unroll
    for (int a = 0; a < 2; ++a)
        #pragma unroll
        for (int b = 0; b < 4; ++b) {
            acc1[a][b] = (f32x4){0.f, 0.f, 0.f, 0.f};
            acc3[a][b] = (f32x4){0.f, 0.f, 0.f, 0.f};
        }

    for (int k0 = 0; k0 < H_DIM; k0 += 64) {
        const int gidx = k0 >> 6;

        // ---- stage X: 128x64 fp32 -> bf16 (2048 float4, 8 per thread) ----
        #pragma unroll
        for (int i = 0; i < 8; ++i) {
            int p = t + 256 * i;
            int row = p >> 4, col = (p & 15) * 4;
            float4 xv = *(const float4*)&X[(size_t)(m0 + row) * H_DIM + k0 + col];
            ushort4 o;
            o.x = f2bf(xv.x); o.y = f2bf(xv.y); o.z = f2bf(xv.z); o.w = f2bf(xv.w);
            *(ushort4*)&sX[row * LK + col] = o;
        }
        // ---- stage W1/W3: 64x64 int32 each, dequant -> bf16 ----
        #pragma unroll
        for (int i = 0; i < 4; ++i) {
            int p = t + 256 * i;
            int row = p >> 4, col = (p & 15) * 4;
            int sidx = (n0 + row) * SG + gidx;

            float s = sc1[sidx], z = zp1[sidx];
            int4 qv = *(const int4*)&W1q[(size_t)(n0 + row) * H_DIM + k0 + col];
            ushort4 o;
            o.x = f2bf(((float)qv.x - z) * s); o.y = f2bf(((float)qv.y - z) * s);
            o.z = f2bf(((float)qv.z - z) * s); o.w = f2bf(((float)qv.w - z) * s);
            *(ushort4*)&sW1[row * LK + col] = o;

            s = sc3[sidx]; z = zp3[sidx];
            qv = *(const int4*)&W3q[(size_t)(n0 + row) * H_DIM + k0 + col];
            o.x = f2bf(((float)qv.x - z) * s); o.y = f2bf(((float)qv.y - z) * s);
            o.z = f2bf(((float)qv.z - z) * s); o.w = f2bf(((float)qv.w - z) * s);
            *(ushort4*)&sW3[row * LK + col] = o;
        }
        __syncthreads();

        // ---- MFMA: wave quadrant mb = wave*32 ----
        const int mb = wave * 32;
        #pragma unroll
        for (int kh = 0; kh < 2; ++kh) {
            const int kb = kh * 32 + q * 8;
            bf16x8 av[2], b1v[4], b3v[4];
            #pragma unroll
            for (int im = 0; im < 2; ++im)
                av[im] = *(const bf16x8*)&sX[(mb + im * 16 + r) * LK + kb];
            #pragma unroll
            for (int j = 0; j < 4; ++j) {
                b1v[j] = *(const bf16x8*)&sW1[(j * 16 + r) * LK + kb];
                b3v[j] = *(const bf16x8*)&sW3[(j * 16 + r) * LK + kb];
            }
            #pragma unroll
            for (int im = 0; im < 2; ++im)
                #pragma unroll
                for (int j = 0; j < 4; ++j) {
                    acc1[im][j] = __builtin_amdgcn_mfma_f32_16x16x32_bf16(av[im], b1v[j], acc1[im][j], 0, 0, 0);
                    acc3[im][j] = __builtin_amdgcn_mfma_f32_16x16x32_bf16(av[im], b3v[j], acc3[im][j], 0, 0, 0);
                }
        }
        __syncthreads();
    }

    // ---- epilogue: silu(a1) * a3 -> bf16 G ----
    const int mb = wave * 32;
    #pragma unroll
    for (int im = 0; im < 2; ++im)
        #pragma unroll
        for (int j = 0; j < 4; ++j)
            #pragma unroll
            for (int reg = 0; reg < 4; ++reg) {
                int m = m0 + mb + im * 16 + q * 4 + reg;   // C/D: row=(lane>>4)*4+reg
                int f = n0 + j * 16 + r;                   //      col=lane&15
                float g1 = acc1[im][j][reg];
                float g3 = acc3[im][j][reg];
                float val = g1 / (1.f + __expf(-g1)) * g3;
                G[(size_t)m * F_DIM + f] = f2bf(val);
            }
}

// ---------------------------------------------------------------------------
// Kernel B: out = G @ W2^T   -> fp32 [T, H]
// Tile: BM=64 (T), BN=64 (H), BK=64. 4 waves, each a 16-row strip x 64 cols.
// ---------------------------------------------------------------------------
__global__ __launch_bounds__(256, 4)
void down_kernel(const unsigned short* __restrict__ G,
                 const int* __restrict__ W2q, const float* __restrict__ sc2,
                 const float* __restrict__ zp2,
                 float* __restrict__ Out)
{
    constexpr int LK = 72;
    __shared__ unsigned short sA[64 * LK];
    __shared__ unsigned short sW[64 * LK];

    const int t    = threadIdx.x;
    const int wave = t >> 6;
    const int lane = t & 63;
    const int r    = lane & 15;
    const int q    = lane >> 4;
    const int m0   = blockIdx.y * 64;
    const int n0   = blockIdx.x * 64;
    const int SG   = F_DIM / 64;  // 224 groups per output row

    f32x4 acc[4];
    #pragma unroll
    for (int j = 0; j < 4; ++j) acc[j] = (f32x4){0.f, 0.f, 0.f, 0.f};

    for (int k0 = 0; k0 < F_DIM; k0 += 64) {
        const int gidx = k0 >> 6;

        // ---- stage A (G, already bf16): 64x64 = 512 int4, 2 per thread ----
        #pragma unroll
        for (int i = 0; i < 2; ++i) {
            int p = t + 256 * i;
            int row = p >> 3, col = (p & 7) * 8;
            int4 v = *(const int4*)&G[(size_t)(m0 + row) * F_DIM + k0 + col];
            *(int4*)&sA[row * LK + col] = v;
        }
        // ---- stage W2: 64x64 int32, dequant -> bf16 ----
        #pragma unroll
        for (int i = 0; i < 4; ++i) {
            int p = t + 256 * i;
            int row = p >> 4, col = (p & 15) * 4;
            int sidx = (n0 + row) * SG + gidx;
            float s = sc2[sidx], z = zp2[sidx];
            int4 qv = *(const int4*)&W2q[(size_t)(n0 + row) * F_DIM + k0 + col];
            ushort4 o;
            o.x = f2bf(((float)qv.x - z) * s); o.y = f2bf(((float)qv.y - z) * s);
            o.z = f2bf(((float)qv.z - z) * s); o.w = f2bf(((float)qv.w - z) * s);
            *(ushort4*)&sW[row * LK + col] = o;
        }
        __syncthreads();

        const int mb = wave * 16;
        #pragma unroll
        for (int kh = 0; kh < 2; ++kh) {
            const int kb = kh * 32 + q * 8;
            bf16x8 a = *(const bf16x8*)&sA[(mb + r) * LK + kb];
            #pragma unroll
            for (int j = 0; j < 4; ++j) {
                bf16x8 b = *(const bf16x8*)&sW[(j * 16 + r) * LK + kb];
                acc[j] = __builtin_amdgcn_mfma_f32_16x16x32_bf16(a, b, acc[j], 0, 0, 0);
            }
        }
        __syncthreads();
    }

    #pragma unroll
    for (int j = 0; j < 4; ++j)
        #pragma unroll
        for (int reg = 0; reg < 4; ++reg) {
            int m = m0 + wave * 16 + q * 4 + reg;
            int h = n0 + j * 16 + r;
            Out[(size_t)m * H_DIM + h] = acc[j][reg];
        }
}

extern "C" void kernel_launch(void* const* d_in, const int* in_sizes, int n_in,
                              void* d_out, int out_size, void* d_ws, size_t ws_size,
                              hipStream_t stream) {
    const float* X   = (const float*)d_in[0];
    const int*   W1q = (const int*)d_in[1];
    const float* s1  = (const float*)d_in[2];
    const float* z1  = (const float*)d_in[3];
    const int*   W3q = (const int*)d_in[4];
    const float* s3  = (const float*)d_in[5];
    const float* z3  = (const float*)d_in[6];
    const int*   W2q = (const int*)d_in[7];
    const float* s2  = (const float*)d_in[8];
    const float* z2  = (const float*)d_in[9];
    float* Out = (float*)d_out;
    unsigned short* G = (unsigned short*)d_ws;  // bf16 [T, F] = 14.7 MB

    gate_up_kernel<<<dim3(F_DIM / 64, T_DIM / 128), 256, 0, stream>>>(
        X, W1q, s1, z1, W3q, s3, z3, G);
    down_kernel<<<dim3(H_DIM / 64, T_DIM / 64), 256, 0, stream>>>(
        G, W2q, s2, z2, Out);
}